// Round 6
// baseline (366.320 us; speedup 1.0000x reference)
//
#include <hip/hip_runtime.h>
#include <hip/hip_bf16.h>

#define S_SEQ 2048
#define R_RES 384
#define CIN   64
#define HC    64
#define NH    8
#define CHD   8

using bf16x8 = __attribute__((ext_vector_type(8))) short;
using f32x4  = __attribute__((ext_vector_type(4))) float;

__device__ __forceinline__ short f2bf(float v) {
  __hip_bfloat16 h = __float2bfloat16(v);
  union { __hip_bfloat16 b; short s; } u; u.b = h; return u.s;
}
__device__ __forceinline__ float bf2f(short s) {
  union { short s; __hip_bfloat16 b; } u; u.s = s; return __bfloat162float(u.b);
}

// ---------------------------------------------------------------------------
// Kernel 0: prep weight tables.
// wgT_perm[a][c] = ln_w[c]*wg[c][pi(a)]   (hi/lo bf16 split)  [GEMM1 A-operand]
// woT[cout][j]   = wo[j][cout]            (hi/lo bf16 split)  [GEMM2 A-operand]
// wkvT[a][c]     = ln_w[c]*[wk|wv][c][a&7] (hi/lo)            [k1 A-operand]
// bg2[j] = bg[j] + sum_c ln_b[c]*wg[c][j]
// bkv[a] = sum_c ln_b[c]*[wk|wv][c][a&7]
// ---------------------------------------------------------------------------
__global__ __launch_bounds__(256) void k0_prep(
    const float* __restrict__ wg, const float* __restrict__ wo,
    const float* __restrict__ wk, const float* __restrict__ wv,
    const float* __restrict__ ln_w, const float* __restrict__ ln_b,
    const float* __restrict__ bg,
    short* __restrict__ wgT_hi, short* __restrict__ wgT_lo,
    short* __restrict__ woT_hi, short* __restrict__ woT_lo,
    short* __restrict__ wkvT_hi, short* __restrict__ wkvT_lo,
    float* __restrict__ bg2, float* __restrict__ bkv) {
  const int idx = blockIdx.x * 256 + threadIdx.x;
  if (idx < HC) {
    float s = bg[idx];
    for (int c = 0; c < CIN; ++c) s += ln_b[c] * wg[c * HC + idx];
    bg2[idx] = s;
  }
  if (idx < 16) {
    float s = 0.f;
    for (int c = 0; c < CIN; ++c)
      s += ln_b[c] * ((idx < 8) ? wk[c * CHD + idx] : wv[c * CHD + (idx - 8)]);
    bkv[idx] = s;
  }
  if (idx < 16 * CIN) {  // wkvT
    const int a = idx >> 6, c = idx & 63;
    const float w = ln_w[c] * ((a < 8) ? wk[c * CHD + a] : wv[c * CHD + (a - 8)]);
    short h = f2bf(w);
    wkvT_hi[idx] = h; wkvT_lo[idx] = f2bf(w - bf2f(h));
  }
  if (idx >= HC * CIN) return;
  const int a = idx >> 6;   // table row
  const int c = idx & 63;   // table col
  const int n = a >> 4, lp = (a >> 2) & 3, i = a & 3;
  const int j = ((n & 2) << 4) + lp * 8 + ((n & 1) << 2) + i;  // pi(a)
  const float g = ln_w[c] * wg[c * HC + j];
  short gh = f2bf(g);
  wgT_hi[idx] = gh; wgT_lo[idx] = f2bf(g - bf2f(gh));
  const float o = wo[c * CIN + a];
  short oh = f2bf(o);
  woT_hi[idx] = oh; woT_lo[idx] = f2bf(o - bf2f(oh));
}

// ---------------------------------------------------------------------------
// Kernel 1 (MFMA): LN + K/V projection + masked pooled sums.
// grid (R_RES, 4); block 256 = 4 waves; wave owns 128 s-rows (8 tiles of 16).
// kv^T = wkvT . xhat^T  (6-MFMA split); pooled sums pre-affine, folded in k2.
// ---------------------------------------------------------------------------
__global__ __launch_bounds__(256, 4) void k1_mfma(
    const float* __restrict__ m, const float* __restrict__ mask,
    const short* __restrict__ wkvT_hi, const short* __restrict__ wkvT_lo,
    const float* __restrict__ bkv,
    float* __restrict__ Kd, float* __restrict__ Vd,
    float* __restrict__ qpool_part, float* __restrict__ qm_part) {
  const int r = blockIdx.x;
  const int chunk = blockIdx.y;  // 0..3
  const int tid = threadIdx.x;
  const int wave = tid >> 6;
  const int lane = tid & 63;
  const int lrow = lane & 15;
  const int lpart = lane >> 4;
  const int s_base = chunk * 512 + wave * 128;

  __shared__ float redA[4][CIN];
  __shared__ float redM[4];

  // persistent A-operand fragments (16 VGPR)
  bf16x8 kvh[2], kvl[2];
  #pragma unroll
  for (int k = 0; k < 2; ++k) {
    const int idx = lrow * 64 + k * 32 + lpart * 8;
    kvh[k] = *reinterpret_cast<const bf16x8*>(wkvT_hi + idx);
    kvl[k] = *reinterpret_cast<const bf16x8*>(wkvT_lo + idx);
  }
  const float4 bkvq = *reinterpret_cast<const float4*>(bkv + lpart * 4);

  float qacc[16];
  #pragma unroll
  for (int e = 0; e < 16; ++e) qacc[e] = 0.f;
  float macc = 0.f;

  for (int t = 0; t < 8; ++t) {
    const int srow = s_base + t * 16 + lrow;
    const float* mrow = m + ((size_t)srow * R_RES + r) * CIN;
    float x0[8], x1[8];
    {
      const float4* p0 = reinterpret_cast<const float4*>(mrow + lpart * 8);
      const float4* p1 = reinterpret_cast<const float4*>(mrow + 32 + lpart * 8);
      float4 a = p0[0], b = p0[1], c = p1[0], d = p1[1];
      x0[0]=a.x; x0[1]=a.y; x0[2]=a.z; x0[3]=a.w; x0[4]=b.x; x0[5]=b.y; x0[6]=b.z; x0[7]=b.w;
      x1[0]=c.x; x1[1]=c.y; x1[2]=c.z; x1[3]=c.w; x1[4]=d.x; x1[5]=d.y; x1[6]=d.z; x1[7]=d.w;
    }
    const float mk = mask[(size_t)srow * R_RES + r];

    float s = 0.f;
    #pragma unroll
    for (int e = 0; e < 8; ++e) s += x0[e] + x1[e];
    s += __shfl_xor(s, 16, 64);
    s += __shfl_xor(s, 32, 64);
    const float mean = s * (1.0f / CIN);
    float vs = 0.f;
    #pragma unroll
    for (int e = 0; e < 8; ++e) {
      float d0 = x0[e] - mean, d1 = x1[e] - mean;
      vs += d0 * d0 + d1 * d1;
    }
    vs += __shfl_xor(vs, 16, 64);
    vs += __shfl_xor(vs, 32, 64);
    const float rstd = rsqrtf(vs * (1.0f / CIN) + 1e-5f);

    bf16x8 ah0, al0, ah1, al1;  // xhat (pre-affine) hi/lo
    #pragma unroll
    for (int e = 0; e < 8; ++e) {
      const float xh0 = (x0[e] - mean) * rstd;
      const float xh1 = (x1[e] - mean) * rstd;
      qacc[e]     += mk * xh0;
      qacc[8 + e] += mk * xh1;
      short h = f2bf(xh0);
      ah0[e] = h; al0[e] = f2bf(xh0 - bf2f(h));
      h = f2bf(xh1);
      ah1[e] = h; al1[e] = f2bf(xh1 - bf2f(h));
    }
    macc += mk;

    f32x4 a = {0.f, 0.f, 0.f, 0.f};
    a = __builtin_amdgcn_mfma_f32_16x16x32_bf16(kvh[0], ah0, a, 0, 0, 0);
    a = __builtin_amdgcn_mfma_f32_16x16x32_bf16(kvh[1], ah1, a, 0, 0, 0);
    a = __builtin_amdgcn_mfma_f32_16x16x32_bf16(kvl[0], ah0, a, 0, 0, 0);
    a = __builtin_amdgcn_mfma_f32_16x16x32_bf16(kvl[1], ah1, a, 0, 0, 0);
    a = __builtin_amdgcn_mfma_f32_16x16x32_bf16(kvh[0], al0, a, 0, 0, 0);
    a = __builtin_amdgcn_mfma_f32_16x16x32_bf16(kvh[1], al1, a, 0, 0, 0);

    // lane owns kv channels [lpart*4, +4) of its own row (col = lrow)
    const size_t off = ((size_t)r * S_SEQ + srow) * CHD + (lpart & 1) * 4;
    float* dst = ((lpart & 2) ? Vd : Kd) + off;
    *reinterpret_cast<float4*>(dst) =
        make_float4(a[0] + bkvq.x, a[1] + bkvq.y, a[2] + bkvq.z, a[3] + bkvq.w);
  }

  // reduce pooled sums across the 16 lrow lanes
  #pragma unroll
  for (int off = 1; off <= 8; off <<= 1) {
    #pragma unroll
    for (int e = 0; e < 16; ++e) qacc[e] += __shfl_xor(qacc[e], off, 64);
    macc += __shfl_xor(macc, off, 64);
  }
  if (lrow == 0) {
    #pragma unroll
    for (int e = 0; e < 8; ++e) {
      redA[wave][lpart * 8 + e] = qacc[e];
      redA[wave][32 + lpart * 8 + e] = qacc[8 + e];
    }
    if (lpart == 0) redM[wave] = macc;
  }
  __syncthreads();
  if (tid < CIN) {
    const float tot = redA[0][tid] + redA[1][tid] + redA[2][tid] + redA[3][tid];
    qpool_part[((size_t)chunk * R_RES + r) * CIN + tid] = tot;
  }
  if (tid == 0)
    qm_part[chunk * R_RES + r] = redM[0] + redM[1] + redM[2] + redM[3];
}

// ---------------------------------------------------------------------------
// Kernel 2: per-residue global attention. grid: R_RES blocks of 256.
// q from k1's pooled partials (gamma/beta folded here); 2-pass softmax on K/V.
// ---------------------------------------------------------------------------
__global__ __launch_bounds__(256) void k2_attn(
    const float* __restrict__ mask,
    const float* __restrict__ ln_w, const float* __restrict__ ln_b,
    const float* __restrict__ wq,
    const float* __restrict__ qpool_part, const float* __restrict__ qm_part,
    const float* __restrict__ Kd, const float* __restrict__ Vd,
    float* __restrict__ od) {
  const int r = blockIdx.x;
  const int tid = threadIdx.x;
  const int lane = tid & 63;
  const int wave = tid >> 6;

  __shared__ float s_q[HC];
  __shared__ float s_qp[CIN];
  __shared__ float redw[4][CIN];
  __shared__ float dred[4][NH];
  __shared__ float mred[4][NH];

  const float msum_tot = qm_part[0 * R_RES + r] + qm_part[1 * R_RES + r] +
                         qm_part[2 * R_RES + r] + qm_part[3 * R_RES + r];

  if (tid < CIN) {
    float A = 0.f;
    #pragma unroll
    for (int ch = 0; ch < 4; ++ch)
      A += qpool_part[((size_t)ch * R_RES + r) * CIN + tid];
    s_qp[tid] = (ln_w[tid] * A + ln_b[tid] * msum_tot) / (msum_tot + 1e-10f);
  }
  __syncthreads();
  if (tid < HC) {
    float qj = 0.f;
    for (int c = 0; c < CIN; ++c) qj += s_qp[c] * wq[c * HC + tid];
    s_q[tid] = qj * 0.35355339059327373f;  // 1/sqrt(8)
  }
  __syncthreads();

  float hmax[NH];
  #pragma unroll
  for (int h = 0; h < NH; ++h) hmax[h] = -1e30f;

  for (int s = tid; s < S_SEQ; s += 256) {
    float kk[CHD];
    const float4* kp = reinterpret_cast<const float4*>(Kd + ((size_t)r * S_SEQ + s) * CHD);
    float4 a = kp[0], b = kp[1];
    kk[0] = a.x; kk[1] = a.y; kk[2] = a.z; kk[3] = a.w;
    kk[4] = b.x; kk[5] = b.y; kk[6] = b.z; kk[7] = b.w;
    const float madd = 1e9f * (mask[(size_t)s * R_RES + r] - 1.0f);
    #pragma unroll
    for (int h = 0; h < NH; ++h) {
      float l = madd;
      #pragma unroll
      for (int j = 0; j < CHD; ++j) l += s_q[h * CHD + j] * kk[j];
      hmax[h] = fmaxf(hmax[h], l);
    }
  }
  #pragma unroll
  for (int h = 0; h < NH; ++h) {
    #pragma unroll
    for (int off = 32; off >= 1; off >>= 1)
      hmax[h] = fmaxf(hmax[h], __shfl_xor(hmax[h], off, 64));
  }
  if (lane == 0) {
    #pragma unroll
    for (int h = 0; h < NH; ++h) mred[wave][h] = hmax[h];
  }
  __syncthreads();
  #pragma unroll
  for (int h = 0; h < NH; ++h)
    hmax[h] = fmaxf(fmaxf(mred[0][h], mred[1][h]), fmaxf(mred[2][h], mred[3][h]));

  float opart[HC];
  #pragma unroll
  for (int i = 0; i < HC; ++i) opart[i] = 0.f;
  float dpart[NH];
  #pragma unroll
  for (int h = 0; h < NH; ++h) dpart[h] = 0.f;

  for (int s = tid; s < S_SEQ; s += 256) {
    float kk[CHD], vv[CHD];
    const float4* kp = reinterpret_cast<const float4*>(Kd + ((size_t)r * S_SEQ + s) * CHD);
    const float4* vp = reinterpret_cast<const float4*>(Vd + ((size_t)r * S_SEQ + s) * CHD);
    float4 a = kp[0], b = kp[1], c4 = vp[0], d4 = vp[1];
    kk[0] = a.x; kk[1] = a.y; kk[2] = a.z; kk[3] = a.w;
    kk[4] = b.x; kk[5] = b.y; kk[6] = b.z; kk[7] = b.w;
    vv[0] = c4.x; vv[1] = c4.y; vv[2] = c4.z; vv[3] = c4.w;
    vv[4] = d4.x; vv[5] = d4.y; vv[6] = d4.z; vv[7] = d4.w;
    const float madd = 1e9f * (mask[(size_t)s * R_RES + r] - 1.0f);
    #pragma unroll
    for (int h = 0; h < NH; ++h) {
      float l = madd;
      #pragma unroll
      for (int j = 0; j < CHD; ++j) l += s_q[h * CHD + j] * kk[j];
      const float p = __expf(l - hmax[h]);
      dpart[h] += p;
      #pragma unroll
      for (int j = 0; j < CHD; ++j) opart[h * CHD + j] += p * vv[j];
    }
  }

  #pragma unroll
  for (int h = 0; h < NH; ++h) {
    float v = dpart[h];
    #pragma unroll
    for (int off = 32; off >= 1; off >>= 1) v += __shfl_xor(v, off, 64);
    dpart[h] = v;
  }
  if (lane == 0) {
    #pragma unroll
    for (int h = 0; h < NH; ++h) dred[wave][h] = dpart[h];
  }
  float keep = 0.f;
  #pragma unroll
  for (int c = 0; c < HC; ++c) {
    float val = opart[c];
    #pragma unroll
    for (int off = 32; off >= 1; off >>= 1) val += __shfl_xor(val, off, 64);
    if (lane == c) keep = val;
  }
  redw[wave][lane] = keep;
  __syncthreads();
  if (tid < HC) {
    const float tot = redw[0][tid] + redw[1][tid] + redw[2][tid] + redw[3][tid];
    const int h = tid >> 3;
    const float den = dred[0][h] + dred[1][h] + dred[2][h] + dred[3][h];
    od[(size_t)r * HC + tid] = tot / den;
  }
}

// ---------------------------------------------------------------------------
// Kernel 3 (MFMA): out = (sigmoid(LN(m)@wg + bg) * o) @ wo + bo
// Weights in XOR-swizzled LDS (frees 64 VGPR -> 4 waves/SIMD tier).
// Register dataflow between GEMMs via pi-permuted wg table (round-4 design).
// ---------------------------------------------------------------------------
__global__ __launch_bounds__(256, 4) void k3_mfma(
    const float* __restrict__ m,
    const short* __restrict__ wgT_hi, const short* __restrict__ wgT_lo,
    const short* __restrict__ woT_hi, const short* __restrict__ woT_lo,
    const float* __restrict__ bg2, const float* __restrict__ bo,
    const float* __restrict__ od, float* __restrict__ out) {
  const int tid = threadIdx.x;
  const int wave = tid >> 6;
  const int lane = tid & 63;
  const int lrow = lane & 15;
  const int lpart = lane >> 4;
  const size_t base = (size_t)blockIdx.x * 256 + (size_t)wave * 64;
  const int base_r = (int)(base % R_RES);  // multiple of 64

  // 0:w1h 1:w1l 2:w2h 3:w2l, each 64x64 bf16, XOR-swizzled rows
  __shared__ short wlds[4][64 * 64];
  {
    const short* srcs[4] = {wgT_hi, wgT_lo, woT_hi, woT_lo};
    #pragma unroll
    for (int tbl = 0; tbl < 4; ++tbl) {
      const short* src = srcs[tbl];
      char* dstb = reinterpret_cast<char*>(wlds[tbl]);
      for (int ch = tid; ch < 512; ch += 256) {
        const int boff = ch * 16;
        const int row = boff >> 7;
        *reinterpret_cast<bf16x8*>(dstb + (boff ^ ((row & 7) << 4))) =
            *reinterpret_cast<const bf16x8*>(src + ch * 8);
      }
    }
  }
  __syncthreads();

  // swizzled LDS fragment read: table row a = n*16+lrow, k-chunk kk
  auto ldw = [&](int tbl, int n, int kk) -> bf16x8 {
    const int row = n * 16 + lrow;
    const int boff = (row * 128 + kk * 64 + lpart * 16) ^ ((row & 7) << 4);
    return *reinterpret_cast<const bf16x8*>(
        reinterpret_cast<const char*>(wlds[tbl]) + boff);
  };

  float4 bgq[4], boq[4];
  bgq[0] = *reinterpret_cast<const float4*>(bg2 + 8 * lpart);
  bgq[1] = *reinterpret_cast<const float4*>(bg2 + 8 * lpart + 4);
  bgq[2] = *reinterpret_cast<const float4*>(bg2 + 32 + 8 * lpart);
  bgq[3] = *reinterpret_cast<const float4*>(bg2 + 36 + 8 * lpart);
  #pragma unroll
  for (int n = 0; n < 4; ++n)
    boq[n] = *reinterpret_cast<const float4*>(bo + n * 16 + lpart * 4);

  #pragma unroll
  for (int mt = 0; mt < 4; ++mt) {
    const int rl = mt * 16 + lrow;
    const size_t grow = base + rl;
    const int r = base_r + rl;  // never wraps
    const float* mrow = m + grow * CIN;

    float x0[8], x1[8];
    {
      const float4* p0 = reinterpret_cast<const float4*>(mrow + lpart * 8);
      const float4* p1 = reinterpret_cast<const float4*>(mrow + 32 + lpart * 8);
      float4 a = p0[0], b = p0[1], c = p1[0], d = p1[1];
      x0[0]=a.x; x0[1]=a.y; x0[2]=a.z; x0[3]=a.w; x0[4]=b.x; x0[5]=b.y; x0[6]=b.z; x0[7]=b.w;
      x1[0]=c.x; x1[1]=c.y; x1[2]=c.z; x1[3]=c.w; x1[4]=d.x; x1[5]=d.y; x1[6]=d.z; x1[7]=d.w;
    }
    float s = 0.f;
    #pragma unroll
    for (int e = 0; e < 8; ++e) s += x0[e] + x1[e];
    s += __shfl_xor(s, 16, 64);
    s += __shfl_xor(s, 32, 64);
    const float mean = s * (1.0f / CIN);
    float vs = 0.f;
    #pragma unroll
    for (int e = 0; e < 8; ++e) {
      float d0 = x0[e] - mean, d1 = x1[e] - mean;
      vs += d0 * d0 + d1 * d1;
    }
    vs += __shfl_xor(vs, 16, 64);
    vs += __shfl_xor(vs, 32, 64);
    const float rstd = rsqrtf(vs * (1.0f / CIN) + 1e-5f);

    bf16x8 ah0, al0, ah1, al1;
    #pragma unroll
    for (int e = 0; e < 8; ++e) {
      float xn = (x0[e] - mean) * rstd;
      short h = f2bf(xn);
      ah0[e] = h; al0[e] = f2bf(xn - bf2f(h));
      xn = (x1[e] - mean) * rstd;
      h = f2bf(xn);
      ah1[e] = h; al1[e] = f2bf(xn - bf2f(h));
    }

    // ---- GEMM1: z^T (weights streamed from LDS) ----
    f32x4 acc[4];
    #pragma unroll
    for (int n = 0; n < 4; ++n) {
      const bf16x8 h0 = ldw(0, n, 0), h1 = ldw(0, n, 1);
      const bf16x8 l0 = ldw(1, n, 0), l1 = ldw(1, n, 1);
      f32x4 a = {0.f, 0.f, 0.f, 0.f};
      a = __builtin_amdgcn_mfma_f32_16x16x32_bf16(h0, ah0, a, 0, 0, 0);
      a = __builtin_amdgcn_mfma_f32_16x16x32_bf16(h1, ah1, a, 0, 0, 0);
      a = __builtin_amdgcn_mfma_f32_16x16x32_bf16(l0, ah0, a, 0, 0, 0);
      a = __builtin_amdgcn_mfma_f32_16x16x32_bf16(l1, ah1, a, 0, 0, 0);
      a = __builtin_amdgcn_mfma_f32_16x16x32_bf16(h0, al0, a, 0, 0, 0);
      a = __builtin_amdgcn_mfma_f32_16x16x32_bf16(h1, al1, a, 0, 0, 0);
      acc[n] = a;
    }

    // ---- epilogue: t = o * sigmoid(z + bg2) ----
    const float* odr = od + (size_t)r * HC;
    float4 odq[4];
    odq[0] = *reinterpret_cast<const float4*>(odr + 8 * lpart);
    odq[1] = *reinterpret_cast<const float4*>(odr + 8 * lpart + 4);
    odq[2] = *reinterpret_cast<const float4*>(odr + 32 + 8 * lpart);
    odq[3] = *reinterpret_cast<const float4*>(odr + 36 + 8 * lpart);

    float tv[4][4];
    #pragma unroll
    for (int n = 0; n < 4; ++n) {
      const float z0 = acc[n][0] + bgq[n].x;
      const float z1 = acc[n][1] + bgq[n].y;
      const float z2 = acc[n][2] + bgq[n].z;
      const float z3 = acc[n][3] + bgq[n].w;
      tv[n][0] = odq[n].x / (1.0f + __expf(-z0));
      tv[n][1] = odq[n].y / (1.0f + __expf(-z1));
      tv[n][2] = odq[n].z / (1.0f + __expf(-z2));
      tv[n][3] = odq[n].w / (1.0f + __expf(-z3));
    }

    bf16x8 th0, th1, tl0, tl1;
    #pragma unroll
    for (int e = 0; e < 4; ++e) {
      short h = f2bf(tv[0][e]); th0[e]     = h; tl0[e]     = f2bf(tv[0][e] - bf2f(h));
      h = f2bf(tv[1][e]);       th0[4 + e] = h; tl0[4 + e] = f2bf(tv[1][e] - bf2f(h));
      h = f2bf(tv[2][e]);       th1[e]     = h; tl1[e]     = f2bf(tv[2][e] - bf2f(h));
      h = f2bf(tv[3][e]);       th1[4 + e] = h; tl1[4 + e] = f2bf(tv[3][e] - bf2f(h));
    }

    // ---- GEMM2: out^T ----
    float* orow = out + grow * CIN;
    #pragma unroll
    for (int n = 0; n < 4; ++n) {
      const bf16x8 h0 = ldw(2, n, 0), h1 = ldw(2, n, 1);
      const bf16x8 l0 = ldw(3, n, 0), l1 = ldw(3, n, 1);
      f32x4 a = {0.f, 0.f, 0.f, 0.f};
      a = __builtin_amdgcn_mfma_f32_16x16x32_bf16(h0, th0, a, 0, 0, 0);
      a = __builtin_amdgcn_mfma_f32_16x16x32_bf16(h1, th1, a, 0, 0, 0);
      a = __builtin_amdgcn_mfma_f32_16x16x32_bf16(l0, th0, a, 0, 0, 0);
      a = __builtin_amdgcn_mfma_f32_16x16x32_bf16(l1, th1, a, 0, 0, 0);
      a = __builtin_amdgcn_mfma_f32_16x16x32_bf16(h0, tl0, a, 0, 0, 0);
      a = __builtin_amdgcn_mfma_f32_16x16x32_bf16(h1, tl1, a, 0, 0, 0);
      *reinterpret_cast<float4*>(orow + n * 16 + lpart * 4) =
          make_float4(a[0] + boq[n].x, a[1] + boq[n].y,
                      a[2] + boq[n].z, a[3] + boq[n].w);
    }
  }
}

// ---------------------------------------------------------------------------
extern "C" void kernel_launch(void* const* d_in, const int* in_sizes, int n_in,
                              void* d_out, int out_size, void* d_ws, size_t ws_size,
                              hipStream_t stream) {
  const float* m    = (const float*)d_in[0];
  const float* mask = (const float*)d_in[1];
  const float* ln_w = (const float*)d_in[2];
  const float* ln_b = (const float*)d_in[3];
  const float* wq   = (const float*)d_in[4];
  const float* wk   = (const float*)d_in[5];
  const float* wv   = (const float*)d_in[6];
  const float* wg   = (const float*)d_in[7];
  const float* bg   = (const float*)d_in[8];
  const float* wo   = (const float*)d_in[9];
  const float* bo   = (const float*)d_in[10];
  float* out = (float*)d_out;

  const size_t sizeK   = (size_t)R_RES * S_SEQ * CHD * sizeof(float);   // 25.2 MB
  const size_t sizeQP  = (size_t)4 * R_RES * CIN * sizeof(float);       // 393 KB
  const size_t sizeQM  = (size_t)4 * R_RES * sizeof(float);
  const size_t sizeO   = (size_t)R_RES * HC * sizeof(float);
  const size_t sizeW   = (size_t)HC * CIN * sizeof(short);              // 8 KB
  const size_t sizeWKV = (size_t)16 * CIN * sizeof(short);              // 2 KB

  char* ws = (char*)d_ws;
  float* Kd         = (float*)(ws);
  float* Vd         = (float*)(ws + sizeK);
  float* qpool_part = (float*)(ws + 2 * sizeK);
  float* qm_part    = (float*)(ws + 2 * sizeK + sizeQP);
  float* od         = (float*)(ws + 2 * sizeK + sizeQP + sizeQM);
  char* wbase       = ws + 2 * sizeK + sizeQP + sizeQM + sizeO;
  short* wgT_hi  = (short*)(wbase);
  short* wgT_lo  = (short*)(wbase + sizeW);
  short* woT_hi  = (short*)(wbase + 2 * sizeW);
  short* woT_lo  = (short*)(wbase + 3 * sizeW);
  short* wkvT_hi = (short*)(wbase + 4 * sizeW);
  short* wkvT_lo = (short*)(wbase + 4 * sizeW + sizeWKV);
  float* bg2     = (float*)(wbase + 4 * sizeW + 2 * sizeWKV);
  float* bkv     = (float*)(wbase + 4 * sizeW + 2 * sizeWKV + HC * sizeof(float));

  k0_prep<<<(HC * CIN + 255) / 256, 256, 0, stream>>>(
      wg, wo, wk, wv, ln_w, ln_b, bg,
      wgT_hi, wgT_lo, woT_hi, woT_lo, wkvT_hi, wkvT_lo, bg2, bkv);

  k1_mfma<<<dim3(R_RES, 4), 256, 0, stream>>>(
      m, mask, wkvT_hi, wkvT_lo, bkv, Kd, Vd, qpool_part, qm_part);

  k2_attn<<<R_RES, 256, 0, stream>>>(
      mask, ln_w, ln_b, wq, qpool_part, qm_part, Kd, Vd, od);

  k3_mfma<<<(S_SEQ * R_RES) / 256, 256, 0, stream>>>(
      m, wgT_hi, wgT_lo, woT_hi, woT_lo, bg2, bo, od, out);
}

// Round 8
// 298.293 us; speedup vs baseline: 1.2281x; 1.2281x over previous
//
#include <hip/hip_runtime.h>
#include <hip/hip_bf16.h>

#define S_SEQ 2048
#define R_RES 384
#define CIN   64
#define HC    64
#define NH    8
#define CHD   8

using bf16x8 = __attribute__((ext_vector_type(8))) short;
using f32x4  = __attribute__((ext_vector_type(4))) float;

__device__ __forceinline__ short f2bf(float v) {
  __hip_bfloat16 h = __float2bfloat16(v);
  union { __hip_bfloat16 b; short s; } u; u.b = h; return u.s;
}
__device__ __forceinline__ float bf2f(short s) {
  union { short s; __hip_bfloat16 b; } u; u.s = s; return __bfloat162float(u.b);
}

// ---------------------------------------------------------------------------
// Kernel 0: prep weight tables (no permutation — k3 uses R2 conventions).
// wgT_fold[j][c] = ln_w[c]*wg[c][j]   (hi/lo bf16 split)  [k3 GEMM1 B-operand]
// woT[cout][j]   = wo[j][cout]        (hi/lo bf16 split)  [k3 GEMM2 B-operand]
// wkvT[a][c]     = ln_w[c]*[wk|wv][c][a&7] (hi/lo)        [k1 A-operand]
// bg2[j] = bg[j] + sum_c ln_b[c]*wg[c][j]
// bkv[a] = sum_c ln_b[c]*[wk|wv][c][a&7]
// ---------------------------------------------------------------------------
__global__ __launch_bounds__(256) void k0_prep(
    const float* __restrict__ wg, const float* __restrict__ wo,
    const float* __restrict__ wk, const float* __restrict__ wv,
    const float* __restrict__ ln_w, const float* __restrict__ ln_b,
    const float* __restrict__ bg,
    short* __restrict__ wgT_hi, short* __restrict__ wgT_lo,
    short* __restrict__ woT_hi, short* __restrict__ woT_lo,
    short* __restrict__ wkvT_hi, short* __restrict__ wkvT_lo,
    float* __restrict__ bg2, float* __restrict__ bkv) {
  const int idx = blockIdx.x * 256 + threadIdx.x;
  if (idx < HC) {
    float s = bg[idx];
    for (int c = 0; c < CIN; ++c) s += ln_b[c] * wg[c * HC + idx];
    bg2[idx] = s;
  }
  if (idx < 16) {
    float s = 0.f;
    for (int c = 0; c < CIN; ++c)
      s += ln_b[c] * ((idx < 8) ? wk[c * CHD + idx] : wv[c * CHD + (idx - 8)]);
    bkv[idx] = s;
  }
  if (idx < 16 * CIN) {  // wkvT
    const int a = idx >> 6, c = idx & 63;
    const float w = ln_w[c] * ((a < 8) ? wk[c * CHD + a] : wv[c * CHD + (a - 8)]);
    short h = f2bf(w);
    wkvT_hi[idx] = h; wkvT_lo[idx] = f2bf(w - bf2f(h));
  }
  if (idx >= HC * CIN) return;
  const int a = idx >> 6;   // table row (j for wgT, cout for woT)
  const int c = idx & 63;   // table col
  const float g = ln_w[c] * wg[c * HC + a];
  short gh = f2bf(g);
  wgT_hi[idx] = gh; wgT_lo[idx] = f2bf(g - bf2f(gh));
  const float o = wo[c * CIN + a];
  short oh = f2bf(o);
  woT_hi[idx] = oh; woT_lo[idx] = f2bf(o - bf2f(oh));
}

// ---------------------------------------------------------------------------
// Kernel 1 (MFMA): LN + K/V projection + masked pooled sums. (round-6, proven)
// ---------------------------------------------------------------------------
__global__ __launch_bounds__(256, 4) void k1_mfma(
    const float* __restrict__ m, const float* __restrict__ mask,
    const short* __restrict__ wkvT_hi, const short* __restrict__ wkvT_lo,
    const float* __restrict__ bkv,
    float* __restrict__ Kd, float* __restrict__ Vd,
    float* __restrict__ qpool_part, float* __restrict__ qm_part) {
  const int r = blockIdx.x;
  const int chunk = blockIdx.y;  // 0..3
  const int tid = threadIdx.x;
  const int wave = tid >> 6;
  const int lane = tid & 63;
  const int lrow = lane & 15;
  const int lpart = lane >> 4;
  const int s_base = chunk * 512 + wave * 128;

  __shared__ float redA[4][CIN];
  __shared__ float redM[4];

  bf16x8 kvh[2], kvl[2];
  #pragma unroll
  for (int k = 0; k < 2; ++k) {
    const int idx = lrow * 64 + k * 32 + lpart * 8;
    kvh[k] = *reinterpret_cast<const bf16x8*>(wkvT_hi + idx);
    kvl[k] = *reinterpret_cast<const bf16x8*>(wkvT_lo + idx);
  }
  const float4 bkvq = *reinterpret_cast<const float4*>(bkv + lpart * 4);

  float qacc[16];
  #pragma unroll
  for (int e = 0; e < 16; ++e) qacc[e] = 0.f;
  float macc = 0.f;

  for (int t = 0; t < 8; ++t) {
    const int srow = s_base + t * 16 + lrow;
    const float* mrow = m + ((size_t)srow * R_RES + r) * CIN;
    float x0[8], x1[8];
    {
      const float4* p0 = reinterpret_cast<const float4*>(mrow + lpart * 8);
      const float4* p1 = reinterpret_cast<const float4*>(mrow + 32 + lpart * 8);
      float4 a = p0[0], b = p0[1], c = p1[0], d = p1[1];
      x0[0]=a.x; x0[1]=a.y; x0[2]=a.z; x0[3]=a.w; x0[4]=b.x; x0[5]=b.y; x0[6]=b.z; x0[7]=b.w;
      x1[0]=c.x; x1[1]=c.y; x1[2]=c.z; x1[3]=c.w; x1[4]=d.x; x1[5]=d.y; x1[6]=d.z; x1[7]=d.w;
    }
    const float mk = mask[(size_t)srow * R_RES + r];

    float s = 0.f;
    #pragma unroll
    for (int e = 0; e < 8; ++e) s += x0[e] + x1[e];
    s += __shfl_xor(s, 16, 64);
    s += __shfl_xor(s, 32, 64);
    const float mean = s * (1.0f / CIN);
    float vs = 0.f;
    #pragma unroll
    for (int e = 0; e < 8; ++e) {
      float d0 = x0[e] - mean, d1 = x1[e] - mean;
      vs += d0 * d0 + d1 * d1;
    }
    vs += __shfl_xor(vs, 16, 64);
    vs += __shfl_xor(vs, 32, 64);
    const float rstd = rsqrtf(vs * (1.0f / CIN) + 1e-5f);

    bf16x8 ah0, al0, ah1, al1;
    #pragma unroll
    for (int e = 0; e < 8; ++e) {
      const float xh0 = (x0[e] - mean) * rstd;
      const float xh1 = (x1[e] - mean) * rstd;
      qacc[e]     += mk * xh0;
      qacc[8 + e] += mk * xh1;
      short h = f2bf(xh0);
      ah0[e] = h; al0[e] = f2bf(xh0 - bf2f(h));
      h = f2bf(xh1);
      ah1[e] = h; al1[e] = f2bf(xh1 - bf2f(h));
    }
    macc += mk;

    f32x4 a = {0.f, 0.f, 0.f, 0.f};
    a = __builtin_amdgcn_mfma_f32_16x16x32_bf16(kvh[0], ah0, a, 0, 0, 0);
    a = __builtin_amdgcn_mfma_f32_16x16x32_bf16(kvh[1], ah1, a, 0, 0, 0);
    a = __builtin_amdgcn_mfma_f32_16x16x32_bf16(kvl[0], ah0, a, 0, 0, 0);
    a = __builtin_amdgcn_mfma_f32_16x16x32_bf16(kvl[1], ah1, a, 0, 0, 0);
    a = __builtin_amdgcn_mfma_f32_16x16x32_bf16(kvh[0], al0, a, 0, 0, 0);
    a = __builtin_amdgcn_mfma_f32_16x16x32_bf16(kvh[1], al1, a, 0, 0, 0);

    const size_t off = ((size_t)r * S_SEQ + srow) * CHD + (lpart & 1) * 4;
    float* dst = ((lpart & 2) ? Vd : Kd) + off;
    *reinterpret_cast<float4*>(dst) =
        make_float4(a[0] + bkvq.x, a[1] + bkvq.y, a[2] + bkvq.z, a[3] + bkvq.w);
  }

  #pragma unroll
  for (int off = 1; off <= 8; off <<= 1) {
    #pragma unroll
    for (int e = 0; e < 16; ++e) qacc[e] += __shfl_xor(qacc[e], off, 64);
    macc += __shfl_xor(macc, off, 64);
  }
  if (lrow == 0) {
    #pragma unroll
    for (int e = 0; e < 8; ++e) {
      redA[wave][lpart * 8 + e] = qacc[e];
      redA[wave][32 + lpart * 8 + e] = qacc[8 + e];
    }
    if (lpart == 0) redM[wave] = macc;
  }
  __syncthreads();
  if (tid < CIN) {
    const float tot = redA[0][tid] + redA[1][tid] + redA[2][tid] + redA[3][tid];
    qpool_part[((size_t)chunk * R_RES + r) * CIN + tid] = tot;
  }
  if (tid == 0)
    qm_part[chunk * R_RES + r] = redM[0] + redM[1] + redM[2] + redM[3];
}

// ---------------------------------------------------------------------------
// Kernel 2: per-residue global attention. (round-6, proven)
// ---------------------------------------------------------------------------
__global__ __launch_bounds__(256) void k2_attn(
    const float* __restrict__ mask,
    const float* __restrict__ ln_w, const float* __restrict__ ln_b,
    const float* __restrict__ wq,
    const float* __restrict__ qpool_part, const float* __restrict__ qm_part,
    const float* __restrict__ Kd, const float* __restrict__ Vd,
    float* __restrict__ od) {
  const int r = blockIdx.x;
  const int tid = threadIdx.x;
  const int lane = tid & 63;
  const int wave = tid >> 6;

  __shared__ float s_q[HC];
  __shared__ float s_qp[CIN];
  __shared__ float redw[4][CIN];
  __shared__ float dred[4][NH];
  __shared__ float mred[4][NH];

  const float msum_tot = qm_part[0 * R_RES + r] + qm_part[1 * R_RES + r] +
                         qm_part[2 * R_RES + r] + qm_part[3 * R_RES + r];

  if (tid < CIN) {
    float A = 0.f;
    #pragma unroll
    for (int ch = 0; ch < 4; ++ch)
      A += qpool_part[((size_t)ch * R_RES + r) * CIN + tid];
    s_qp[tid] = (ln_w[tid] * A + ln_b[tid] * msum_tot) / (msum_tot + 1e-10f);
  }
  __syncthreads();
  if (tid < HC) {
    float qj = 0.f;
    for (int c = 0; c < CIN; ++c) qj += s_qp[c] * wq[c * HC + tid];
    s_q[tid] = qj * 0.35355339059327373f;  // 1/sqrt(8)
  }
  __syncthreads();

  float hmax[NH];
  #pragma unroll
  for (int h = 0; h < NH; ++h) hmax[h] = -1e30f;

  for (int s = tid; s < S_SEQ; s += 256) {
    float kk[CHD];
    const float4* kp = reinterpret_cast<const float4*>(Kd + ((size_t)r * S_SEQ + s) * CHD);
    float4 a = kp[0], b = kp[1];
    kk[0] = a.x; kk[1] = a.y; kk[2] = a.z; kk[3] = a.w;
    kk[4] = b.x; kk[5] = b.y; kk[6] = b.z; kk[7] = b.w;
    const float madd = 1e9f * (mask[(size_t)s * R_RES + r] - 1.0f);
    #pragma unroll
    for (int h = 0; h < NH; ++h) {
      float l = madd;
      #pragma unroll
      for (int j = 0; j < CHD; ++j) l += s_q[h * CHD + j] * kk[j];
      hmax[h] = fmaxf(hmax[h], l);
    }
  }
  #pragma unroll
  for (int h = 0; h < NH; ++h) {
    #pragma unroll
    for (int off = 32; off >= 1; off >>= 1)
      hmax[h] = fmaxf(hmax[h], __shfl_xor(hmax[h], off, 64));
  }
  if (lane == 0) {
    #pragma unroll
    for (int h = 0; h < NH; ++h) mred[wave][h] = hmax[h];
  }
  __syncthreads();
  #pragma unroll
  for (int h = 0; h < NH; ++h)
    hmax[h] = fmaxf(fmaxf(mred[0][h], mred[1][h]), fmaxf(mred[2][h], mred[3][h]));

  float opart[HC];
  #pragma unroll
  for (int i = 0; i < HC; ++i) opart[i] = 0.f;
  float dpart[NH];
  #pragma unroll
  for (int h = 0; h < NH; ++h) dpart[h] = 0.f;

  for (int s = tid; s < S_SEQ; s += 256) {
    float kk[CHD], vv[CHD];
    const float4* kp = reinterpret_cast<const float4*>(Kd + ((size_t)r * S_SEQ + s) * CHD);
    const float4* vp = reinterpret_cast<const float4*>(Vd + ((size_t)r * S_SEQ + s) * CHD);
    float4 a = kp[0], b = kp[1], c4 = vp[0], d4 = vp[1];
    kk[0] = a.x; kk[1] = a.y; kk[2] = a.z; kk[3] = a.w;
    kk[4] = b.x; kk[5] = b.y; kk[6] = b.z; kk[7] = b.w;
    vv[0] = c4.x; vv[1] = c4.y; vv[2] = c4.z; vv[3] = c4.w;
    vv[4] = d4.x; vv[5] = d4.y; vv[6] = d4.z; vv[7] = d4.w;
    const float madd = 1e9f * (mask[(size_t)s * R_RES + r] - 1.0f);
    #pragma unroll
    for (int h = 0; h < NH; ++h) {
      float l = madd;
      #pragma unroll
      for (int j = 0; j < CHD; ++j) l += s_q[h * CHD + j] * kk[j];
      const float p = __expf(l - hmax[h]);
      dpart[h] += p;
      #pragma unroll
      for (int j = 0; j < CHD; ++j) opart[h * CHD + j] += p * vv[j];
    }
  }

  #pragma unroll
  for (int h = 0; h < NH; ++h) {
    float v = dpart[h];
    #pragma unroll
    for (int off = 32; off >= 1; off >>= 1) v += __shfl_xor(v, off, 64);
    dpart[h] = v;
  }
  if (lane == 0) {
    #pragma unroll
    for (int h = 0; h < NH; ++h) dred[wave][h] = dpart[h];
  }
  float keep = 0.f;
  #pragma unroll
  for (int c = 0; c < HC; ++c) {
    float val = opart[c];
    #pragma unroll
    for (int off = 32; off >= 1; off >>= 1) val += __shfl_xor(val, off, 64);
    if (lane == c) keep = val;
  }
  redw[wave][lane] = keep;
  __syncthreads();
  if (tid < HC) {
    const float tot = redw[0][tid] + redw[1][tid] + redw[2][tid] + redw[3][tid];
    const int h = tid >> 3;
    const float den = dred[0][h] + dred[1][h] + dred[2][h] + dred[3][h];
    od[(size_t)r * HC + tid] = tot / den;
  }
}

// ---------------------------------------------------------------------------
// Kernel 3 (MFMA): round-2 structure (proven) + gamma/beta folding.
// MFMA operand order: mfma(x_frag, w_frag, acc) — A = data rows, B = weight
// table rows as columns. C/D: col = n*16+lrow, row = mt*16+lpart*4+i.
// Block = 128 threads (2 waves); wave owns 64 rows (4 m-tiles of 16).
// ---------------------------------------------------------------------------
__global__ __launch_bounds__(128) void k3_mfma(
    const float* __restrict__ m,
    const short* __restrict__ wgT_hi, const short* __restrict__ wgT_lo,
    const short* __restrict__ woT_hi, const short* __restrict__ woT_lo,
    const float* __restrict__ bg2, const float* __restrict__ bo,
    const float* __restrict__ od, float* __restrict__ out) {
  const int tid = threadIdx.x;
  const int wave = tid >> 6;
  const int lane = tid & 63;
  const int lrow = lane & 15;   // A/B frag row index
  const int lpart = lane >> 4;  // 0..3, k-chunk owner
  const size_t base = (size_t)blockIdx.x * 128 + (size_t)wave * 64;
  const int base_r = (int)(base % R_RES);

  __shared__ float t_lds[2][64 * 64];  // per-wave t tile, XOR-swizzled rows
  float* tw = t_lds[wave];

  // per-lane bias values for columns j = n*16 + lrow
  float bgv[4], bov[4];
  #pragma unroll
  for (int n = 0; n < 4; ++n) { bgv[n] = bg2[n * 16 + lrow]; bov[n] = bo[n * 16 + lrow]; }

  // ---- B1 frags (wgT_fold hi/lo): [n][k]
  bf16x8 b1h[4][2], b1l[4][2];
  #pragma unroll
  for (int n = 0; n < 4; ++n) {
    #pragma unroll
    for (int k = 0; k < 2; ++k) {
      const int idx = (n * 16 + lrow) * 64 + k * 32 + lpart * 8;
      b1h[n][k] = *reinterpret_cast<const bf16x8*>(wgT_hi + idx);
      b1l[n][k] = *reinterpret_cast<const bf16x8*>(wgT_lo + idx);
    }
  }

  // ---- Pass 1: LN -> GEMM1 -> sigmoid*o -> t to LDS ----
  #pragma unroll
  for (int mt = 0; mt < 4; ++mt) {
    const size_t grow = base + mt * 16 + lrow;
    const float* mrow = m + grow * CIN;
    float x0[8], x1[8];
    {
      const float4* p0 = reinterpret_cast<const float4*>(mrow + lpart * 8);
      const float4* p1 = reinterpret_cast<const float4*>(mrow + 32 + lpart * 8);
      float4 a = p0[0], b = p0[1], c = p1[0], d = p1[1];
      x0[0]=a.x; x0[1]=a.y; x0[2]=a.z; x0[3]=a.w; x0[4]=b.x; x0[5]=b.y; x0[6]=b.z; x0[7]=b.w;
      x1[0]=c.x; x1[1]=c.y; x1[2]=c.z; x1[3]=c.w; x1[4]=d.x; x1[5]=d.y; x1[6]=d.z; x1[7]=d.w;
    }
    float s = 0.f;
    #pragma unroll
    for (int e = 0; e < 8; ++e) s += x0[e] + x1[e];
    s += __shfl_xor(s, 16, 64);
    s += __shfl_xor(s, 32, 64);
    const float mean = s * (1.0f / CIN);
    float vs = 0.f;
    #pragma unroll
    for (int e = 0; e < 8; ++e) {
      float d0 = x0[e] - mean, d1 = x1[e] - mean;
      vs += d0 * d0 + d1 * d1;
    }
    vs += __shfl_xor(vs, 16, 64);
    vs += __shfl_xor(vs, 32, 64);
    const float rstd = rsqrtf(vs * (1.0f / CIN) + 1e-5f);

    bf16x8 ah0, al0, ah1, al1;  // xhat (pre-affine) hi/lo
    #pragma unroll
    for (int e = 0; e < 8; ++e) {
      float xn = (x0[e] - mean) * rstd;
      short h = f2bf(xn);
      ah0[e] = h; al0[e] = f2bf(xn - bf2f(h));
      xn = (x1[e] - mean) * rstd;
      h = f2bf(xn);
      ah1[e] = h; al1[e] = f2bf(xn - bf2f(h));
    }

    #pragma unroll
    for (int n = 0; n < 4; ++n) {
      f32x4 acc = {0.f, 0.f, 0.f, 0.f};
      acc = __builtin_amdgcn_mfma_f32_16x16x32_bf16(ah0, b1h[n][0], acc, 0, 0, 0);
      acc = __builtin_amdgcn_mfma_f32_16x16x32_bf16(ah1, b1h[n][1], acc, 0, 0, 0);
      acc = __builtin_amdgcn_mfma_f32_16x16x32_bf16(ah0, b1l[n][0], acc, 0, 0, 0);
      acc = __builtin_amdgcn_mfma_f32_16x16x32_bf16(ah1, b1l[n][1], acc, 0, 0, 0);
      acc = __builtin_amdgcn_mfma_f32_16x16x32_bf16(al0, b1h[n][0], acc, 0, 0, 0);
      acc = __builtin_amdgcn_mfma_f32_16x16x32_bf16(al1, b1h[n][1], acc, 0, 0, 0);
      const int j = n * 16 + lrow;
      #pragma unroll
      for (int i = 0; i < 4; ++i) {
        const int rl = mt * 16 + lpart * 4 + i;
        int r = base_r + rl; if (r >= R_RES) r -= R_RES;
        const float z = acc[i] + bgv[n];
        const float g = 1.0f / (1.0f + __expf(-z));
        const float t = g * od[(size_t)r * HC + j];
        const int off = ((rl * 256 + j * 4)) ^ ((rl & 7) << 4);
        *reinterpret_cast<float*>(reinterpret_cast<char*>(tw) + off) = t;
      }
    }
  }

  __syncthreads();

  // ---- B2 frags (woT hi/lo) replace B1 ----
  bf16x8 b2h[4][2], b2l[4][2];
  #pragma unroll
  for (int n = 0; n < 4; ++n) {
    #pragma unroll
    for (int k = 0; k < 2; ++k) {
      const int idx = (n * 16 + lrow) * 64 + k * 32 + lpart * 8;
      b2h[n][k] = *reinterpret_cast<const bf16x8*>(woT_hi + idx);
      b2l[n][k] = *reinterpret_cast<const bf16x8*>(woT_lo + idx);
    }
  }

  // ---- Pass 2: t -> GEMM2 -> out ----
  #pragma unroll
  for (int mt = 0; mt < 4; ++mt) {
    const int rl2 = mt * 16 + lrow;
    const int swz = (rl2 & 7) << 4;
    bf16x8 ah0, al0, ah1, al1;
    {
      const int a0 = rl2 * 256 + lpart * 32;         // k-chunk 0: j = lpart*8..
      const int a1 = rl2 * 256 + 128 + lpart * 32;   // k-chunk 1: j = 32+lpart*8..
      char* tb = reinterpret_cast<char*>(tw);
      float4 u0 = *reinterpret_cast<float4*>(tb + (a0 ^ swz));
      float4 u1 = *reinterpret_cast<float4*>(tb + ((a0 + 16) ^ swz));
      float4 u2 = *reinterpret_cast<float4*>(tb + (a1 ^ swz));
      float4 u3 = *reinterpret_cast<float4*>(tb + ((a1 + 16) ^ swz));
      float t0[8] = {u0.x, u0.y, u0.z, u0.w, u1.x, u1.y, u1.z, u1.w};
      float t1[8] = {u2.x, u2.y, u2.z, u2.w, u3.x, u3.y, u3.z, u3.w};
      #pragma unroll
      for (int e = 0; e < 8; ++e) {
        short h = f2bf(t0[e]);
        ah0[e] = h; al0[e] = f2bf(t0[e] - bf2f(h));
        h = f2bf(t1[e]);
        ah1[e] = h; al1[e] = f2bf(t1[e] - bf2f(h));
      }
    }
    #pragma unroll
    for (int n = 0; n < 4; ++n) {
      f32x4 acc = {0.f, 0.f, 0.f, 0.f};
      acc = __builtin_amdgcn_mfma_f32_16x16x32_bf16(ah0, b2h[n][0], acc, 0, 0, 0);
      acc = __builtin_amdgcn_mfma_f32_16x16x32_bf16(ah1, b2h[n][1], acc, 0, 0, 0);
      acc = __builtin_amdgcn_mfma_f32_16x16x32_bf16(ah0, b2l[n][0], acc, 0, 0, 0);
      acc = __builtin_amdgcn_mfma_f32_16x16x32_bf16(ah1, b2l[n][1], acc, 0, 0, 0);
      acc = __builtin_amdgcn_mfma_f32_16x16x32_bf16(al0, b2h[n][0], acc, 0, 0, 0);
      acc = __builtin_amdgcn_mfma_f32_16x16x32_bf16(al1, b2h[n][1], acc, 0, 0, 0);
      const int cc = n * 16 + lrow;
      #pragma unroll
      for (int i = 0; i < 4; ++i) {
        const size_t grow = base + mt * 16 + lpart * 4 + i;
        out[grow * CIN + cc] = acc[i] + bov[n];
      }
    }
  }
}

// ---------------------------------------------------------------------------
extern "C" void kernel_launch(void* const* d_in, const int* in_sizes, int n_in,
                              void* d_out, int out_size, void* d_ws, size_t ws_size,
                              hipStream_t stream) {
  const float* m    = (const float*)d_in[0];
  const float* mask = (const float*)d_in[1];
  const float* ln_w = (const float*)d_in[2];
  const float* ln_b = (const float*)d_in[3];
  const float* wq   = (const float*)d_in[4];
  const float* wk   = (const float*)d_in[5];
  const float* wv   = (const float*)d_in[6];
  const float* wg   = (const float*)d_in[7];
  const float* bg   = (const float*)d_in[8];
  const float* wo   = (const float*)d_in[9];
  const float* bo   = (const float*)d_in[10];
  float* out = (float*)d_out;

  const size_t sizeK   = (size_t)R_RES * S_SEQ * CHD * sizeof(float);   // 25.2 MB
  const size_t sizeQP  = (size_t)4 * R_RES * CIN * sizeof(float);       // 393 KB
  const size_t sizeQM  = (size_t)4 * R_RES * sizeof(float);
  const size_t sizeO   = (size_t)R_RES * HC * sizeof(float);
  const size_t sizeW   = (size_t)HC * CIN * sizeof(short);              // 8 KB
  const size_t sizeWKV = (size_t)16 * CIN * sizeof(short);              // 2 KB

  char* ws = (char*)d_ws;
  float* Kd         = (float*)(ws);
  float* Vd         = (float*)(ws + sizeK);
  float* qpool_part = (float*)(ws + 2 * sizeK);
  float* qm_part    = (float*)(ws + 2 * sizeK + sizeQP);
  float* od         = (float*)(ws + 2 * sizeK + sizeQP + sizeQM);
  char* wbase       = ws + 2 * sizeK + sizeQP + sizeQM + sizeO;
  short* wgT_hi  = (short*)(wbase);
  short* wgT_lo  = (short*)(wbase + sizeW);
  short* woT_hi  = (short*)(wbase + 2 * sizeW);
  short* woT_lo  = (short*)(wbase + 3 * sizeW);
  short* wkvT_hi = (short*)(wbase + 4 * sizeW);
  short* wkvT_lo = (short*)(wbase + 4 * sizeW + sizeWKV);
  float* bg2     = (float*)(wbase + 4 * sizeW + 2 * sizeWKV);
  float* bkv     = (float*)(wbase + 4 * sizeW + 2 * sizeWKV + HC * sizeof(float));

  k0_prep<<<(HC * CIN + 255) / 256, 256, 0, stream>>>(
      wg, wo, wk, wv, ln_w, ln_b, bg,
      wgT_hi, wgT_lo, woT_hi, woT_lo, wkvT_hi, wkvT_lo, bg2, bkv);

  k1_mfma<<<dim3(R_RES, 4), 256, 0, stream>>>(
      m, mask, wkvT_hi, wkvT_lo, bkv, Kd, Vd, qpool_part, qm_part);

  k2_attn<<<R_RES, 256, 0, stream>>>(
      mask, ln_w, ln_b, wq, qpool_part, qm_part, Kd, Vd, od);

  k3_mfma<<<(S_SEQ * R_RES) / 128, 128, 0, stream>>>(
      m, wgT_hi, wgT_lo, woT_hi, woT_lo, bg2, bo, od, out);
}

// Round 9
// 223.917 us; speedup vs baseline: 1.6360x; 1.3322x over previous
//
#include <hip/hip_runtime.h>
#include <hip/hip_bf16.h>

#define S_SEQ 2048
#define R_RES 384
#define CIN   64
#define HC    64
#define NH    8
#define CHD   8

using bf16x8 = __attribute__((ext_vector_type(8))) short;
using f32x4  = __attribute__((ext_vector_type(4))) float;

__device__ __forceinline__ short f2bf(float v) {
  __hip_bfloat16 h = __float2bfloat16(v);
  union { __hip_bfloat16 b; short s; } u; u.b = h; return u.s;
}
__device__ __forceinline__ float bf2f(short s) {
  union { short s; __hip_bfloat16 b; } u; u.s = s; return __bfloat162float(u.b);
}

// ---------------------------------------------------------------------------
// Kernel 0: prep weight tables.
// wgT[j][c] = wg[c][j]; woT[cout][j] = wo[j][cout]  (hi/lo bf16, UNFOLDED — R2)
// wkvT[a][c] = ln_w[c]*[wk|wv][c][a&7] (hi/lo, folded — k1 uses pre-affine xhat)
// bkv[a] = sum_c ln_b[c]*[wk|wv][c][a&7]
// ---------------------------------------------------------------------------
__global__ __launch_bounds__(256) void k0_prep(
    const float* __restrict__ wg, const float* __restrict__ wo,
    const float* __restrict__ wk, const float* __restrict__ wv,
    const float* __restrict__ ln_w, const float* __restrict__ ln_b,
    short* __restrict__ wgT_hi, short* __restrict__ wgT_lo,
    short* __restrict__ woT_hi, short* __restrict__ woT_lo,
    short* __restrict__ wkvT_hi, short* __restrict__ wkvT_lo,
    float* __restrict__ bkv) {
  const int idx = blockIdx.x * 256 + threadIdx.x;
  if (idx < 16) {
    float s = 0.f;
    for (int c = 0; c < CIN; ++c)
      s += ln_b[c] * ((idx < 8) ? wk[c * CHD + idx] : wv[c * CHD + (idx - 8)]);
    bkv[idx] = s;
  }
  if (idx < 16 * CIN) {  // wkvT (folded)
    const int a = idx >> 6, c = idx & 63;
    const float w = ln_w[c] * ((a < 8) ? wk[c * CHD + a] : wv[c * CHD + (a - 8)]);
    short h = f2bf(w);
    wkvT_hi[idx] = h; wkvT_lo[idx] = f2bf(w - bf2f(h));
  }
  if (idx >= HC * CIN) return;
  const int a = idx >> 6;   // out row
  const int b = idx & 63;   // out col
  const float g = wg[b * HC + a];
  short gh = f2bf(g);
  wgT_hi[idx] = gh; wgT_lo[idx] = f2bf(g - bf2f(gh));
  const float o = wo[b * CIN + a];
  short oh = f2bf(o);
  woT_hi[idx] = oh; woT_lo[idx] = f2bf(o - bf2f(oh));
}

// ---------------------------------------------------------------------------
// Kernel 1 (MFMA): LN + K/V projection + masked pooled sums. (R6/R8, proven 94us combined)
// ---------------------------------------------------------------------------
__global__ __launch_bounds__(256, 4) void k1_mfma(
    const float* __restrict__ m, const float* __restrict__ mask,
    const short* __restrict__ wkvT_hi, const short* __restrict__ wkvT_lo,
    const float* __restrict__ bkv,
    float* __restrict__ Kd, float* __restrict__ Vd,
    float* __restrict__ qpool_part, float* __restrict__ qm_part) {
  const int r = blockIdx.x;
  const int chunk = blockIdx.y;  // 0..3
  const int tid = threadIdx.x;
  const int wave = tid >> 6;
  const int lane = tid & 63;
  const int lrow = lane & 15;
  const int lpart = lane >> 4;
  const int s_base = chunk * 512 + wave * 128;

  __shared__ float redA[4][CIN];
  __shared__ float redM[4];

  bf16x8 kvh[2], kvl[2];
  #pragma unroll
  for (int k = 0; k < 2; ++k) {
    const int idx = lrow * 64 + k * 32 + lpart * 8;
    kvh[k] = *reinterpret_cast<const bf16x8*>(wkvT_hi + idx);
    kvl[k] = *reinterpret_cast<const bf16x8*>(wkvT_lo + idx);
  }
  const float4 bkvq = *reinterpret_cast<const float4*>(bkv + lpart * 4);

  float qacc[16];
  #pragma unroll
  for (int e = 0; e < 16; ++e) qacc[e] = 0.f;
  float macc = 0.f;

  for (int t = 0; t < 8; ++t) {
    const int srow = s_base + t * 16 + lrow;
    const float* mrow = m + ((size_t)srow * R_RES + r) * CIN;
    float x0[8], x1[8];
    {
      const float4* p0 = reinterpret_cast<const float4*>(mrow + lpart * 8);
      const float4* p1 = reinterpret_cast<const float4*>(mrow + 32 + lpart * 8);
      float4 a = p0[0], b = p0[1], c = p1[0], d = p1[1];
      x0[0]=a.x; x0[1]=a.y; x0[2]=a.z; x0[3]=a.w; x0[4]=b.x; x0[5]=b.y; x0[6]=b.z; x0[7]=b.w;
      x1[0]=c.x; x1[1]=c.y; x1[2]=c.z; x1[3]=c.w; x1[4]=d.x; x1[5]=d.y; x1[6]=d.z; x1[7]=d.w;
    }
    const float mk = mask[(size_t)srow * R_RES + r];

    float s = 0.f;
    #pragma unroll
    for (int e = 0; e < 8; ++e) s += x0[e] + x1[e];
    s += __shfl_xor(s, 16, 64);
    s += __shfl_xor(s, 32, 64);
    const float mean = s * (1.0f / CIN);
    float vs = 0.f;
    #pragma unroll
    for (int e = 0; e < 8; ++e) {
      float d0 = x0[e] - mean, d1 = x1[e] - mean;
      vs += d0 * d0 + d1 * d1;
    }
    vs += __shfl_xor(vs, 16, 64);
    vs += __shfl_xor(vs, 32, 64);
    const float rstd = rsqrtf(vs * (1.0f / CIN) + 1e-5f);

    bf16x8 ah0, al0, ah1, al1;
    #pragma unroll
    for (int e = 0; e < 8; ++e) {
      const float xh0 = (x0[e] - mean) * rstd;
      const float xh1 = (x1[e] - mean) * rstd;
      qacc[e]     += mk * xh0;
      qacc[8 + e] += mk * xh1;
      short h = f2bf(xh0);
      ah0[e] = h; al0[e] = f2bf(xh0 - bf2f(h));
      h = f2bf(xh1);
      ah1[e] = h; al1[e] = f2bf(xh1 - bf2f(h));
    }
    macc += mk;

    f32x4 a = {0.f, 0.f, 0.f, 0.f};
    a = __builtin_amdgcn_mfma_f32_16x16x32_bf16(kvh[0], ah0, a, 0, 0, 0);
    a = __builtin_amdgcn_mfma_f32_16x16x32_bf16(kvh[1], ah1, a, 0, 0, 0);
    a = __builtin_amdgcn_mfma_f32_16x16x32_bf16(kvl[0], ah0, a, 0, 0, 0);
    a = __builtin_amdgcn_mfma_f32_16x16x32_bf16(kvl[1], ah1, a, 0, 0, 0);
    a = __builtin_amdgcn_mfma_f32_16x16x32_bf16(kvh[0], al0, a, 0, 0, 0);
    a = __builtin_amdgcn_mfma_f32_16x16x32_bf16(kvh[1], al1, a, 0, 0, 0);

    const size_t off = ((size_t)r * S_SEQ + srow) * CHD + (lpart & 1) * 4;
    float* dst = ((lpart & 2) ? Vd : Kd) + off;
    *reinterpret_cast<float4*>(dst) =
        make_float4(a[0] + bkvq.x, a[1] + bkvq.y, a[2] + bkvq.z, a[3] + bkvq.w);
  }

  #pragma unroll
  for (int off = 1; off <= 8; off <<= 1) {
    #pragma unroll
    for (int e = 0; e < 16; ++e) qacc[e] += __shfl_xor(qacc[e], off, 64);
    macc += __shfl_xor(macc, off, 64);
  }
  if (lrow == 0) {
    #pragma unroll
    for (int e = 0; e < 8; ++e) {
      redA[wave][lpart * 8 + e] = qacc[e];
      redA[wave][32 + lpart * 8 + e] = qacc[8 + e];
    }
    if (lpart == 0) redM[wave] = macc;
  }
  __syncthreads();
  if (tid < CIN) {
    const float tot = redA[0][tid] + redA[1][tid] + redA[2][tid] + redA[3][tid];
    qpool_part[((size_t)chunk * R_RES + r) * CIN + tid] = tot;
  }
  if (tid == 0)
    qm_part[chunk * R_RES + r] = redM[0] + redM[1] + redM[2] + redM[3];
}

// ---------------------------------------------------------------------------
// Kernel 2: per-residue global attention. (R6/R8, proven)
// ---------------------------------------------------------------------------
__global__ __launch_bounds__(256) void k2_attn(
    const float* __restrict__ mask,
    const float* __restrict__ ln_w, const float* __restrict__ ln_b,
    const float* __restrict__ wq,
    const float* __restrict__ qpool_part, const float* __restrict__ qm_part,
    const float* __restrict__ Kd, const float* __restrict__ Vd,
    float* __restrict__ od) {
  const int r = blockIdx.x;
  const int tid = threadIdx.x;
  const int lane = tid & 63;
  const int wave = tid >> 6;

  __shared__ float s_q[HC];
  __shared__ float s_qp[CIN];
  __shared__ float redw[4][CIN];
  __shared__ float dred[4][NH];
  __shared__ float mred[4][NH];

  const float msum_tot = qm_part[0 * R_RES + r] + qm_part[1 * R_RES + r] +
                         qm_part[2 * R_RES + r] + qm_part[3 * R_RES + r];

  if (tid < CIN) {
    float A = 0.f;
    #pragma unroll
    for (int ch = 0; ch < 4; ++ch)
      A += qpool_part[((size_t)ch * R_RES + r) * CIN + tid];
    s_qp[tid] = (ln_w[tid] * A + ln_b[tid] * msum_tot) / (msum_tot + 1e-10f);
  }
  __syncthreads();
  if (tid < HC) {
    float qj = 0.f;
    for (int c = 0; c < CIN; ++c) qj += s_qp[c] * wq[c * HC + tid];
    s_q[tid] = qj * 0.35355339059327373f;  // 1/sqrt(8)
  }
  __syncthreads();

  float hmax[NH];
  #pragma unroll
  for (int h = 0; h < NH; ++h) hmax[h] = -1e30f;

  for (int s = tid; s < S_SEQ; s += 256) {
    float kk[CHD];
    const float4* kp = reinterpret_cast<const float4*>(Kd + ((size_t)r * S_SEQ + s) * CHD);
    float4 a = kp[0], b = kp[1];
    kk[0] = a.x; kk[1] = a.y; kk[2] = a.z; kk[3] = a.w;
    kk[4] = b.x; kk[5] = b.y; kk[6] = b.z; kk[7] = b.w;
    const float madd = 1e9f * (mask[(size_t)s * R_RES + r] - 1.0f);
    #pragma unroll
    for (int h = 0; h < NH; ++h) {
      float l = madd;
      #pragma unroll
      for (int j = 0; j < CHD; ++j) l += s_q[h * CHD + j] * kk[j];
      hmax[h] = fmaxf(hmax[h], l);
    }
  }
  #pragma unroll
  for (int h = 0; h < NH; ++h) {
    #pragma unroll
    for (int off = 32; off >= 1; off >>= 1)
      hmax[h] = fmaxf(hmax[h], __shfl_xor(hmax[h], off, 64));
  }
  if (lane == 0) {
    #pragma unroll
    for (int h = 0; h < NH; ++h) mred[wave][h] = hmax[h];
  }
  __syncthreads();
  #pragma unroll
  for (int h = 0; h < NH; ++h)
    hmax[h] = fmaxf(fmaxf(mred[0][h], mred[1][h]), fmaxf(mred[2][h], mred[3][h]));

  float opart[HC];
  #pragma unroll
  for (int i = 0; i < HC; ++i) opart[i] = 0.f;
  float dpart[NH];
  #pragma unroll
  for (int h = 0; h < NH; ++h) dpart[h] = 0.f;

  for (int s = tid; s < S_SEQ; s += 256) {
    float kk[CHD], vv[CHD];
    const float4* kp = reinterpret_cast<const float4*>(Kd + ((size_t)r * S_SEQ + s) * CHD);
    const float4* vp = reinterpret_cast<const float4*>(Vd + ((size_t)r * S_SEQ + s) * CHD);
    float4 a = kp[0], b = kp[1], c4 = vp[0], d4 = vp[1];
    kk[0] = a.x; kk[1] = a.y; kk[2] = a.z; kk[3] = a.w;
    kk[4] = b.x; kk[5] = b.y; kk[6] = b.z; kk[7] = b.w;
    vv[0] = c4.x; vv[1] = c4.y; vv[2] = c4.z; vv[3] = c4.w;
    vv[4] = d4.x; vv[5] = d4.y; vv[6] = d4.z; vv[7] = d4.w;
    const float madd = 1e9f * (mask[(size_t)s * R_RES + r] - 1.0f);
    #pragma unroll
    for (int h = 0; h < NH; ++h) {
      float l = madd;
      #pragma unroll
      for (int j = 0; j < CHD; ++j) l += s_q[h * CHD + j] * kk[j];
      const float p = __expf(l - hmax[h]);
      dpart[h] += p;
      #pragma unroll
      for (int j = 0; j < CHD; ++j) opart[h * CHD + j] += p * vv[j];
    }
  }

  #pragma unroll
  for (int h = 0; h < NH; ++h) {
    float v = dpart[h];
    #pragma unroll
    for (int off = 32; off >= 1; off >>= 1) v += __shfl_xor(v, off, 64);
    dpart[h] = v;
  }
  if (lane == 0) {
    #pragma unroll
    for (int h = 0; h < NH; ++h) dred[wave][h] = dpart[h];
  }
  float keep = 0.f;
  #pragma unroll
  for (int c = 0; c < HC; ++c) {
    float val = opart[c];
    #pragma unroll
    for (int off = 32; off >= 1; off >>= 1) val += __shfl_xor(val, off, 64);
    if (lane == c) keep = val;
  }
  redw[wave][lane] = keep;
  __syncthreads();
  if (tid < HC) {
    const float tot = redw[0][tid] + redw[1][tid] + redw[2][tid] + redw[3][tid];
    const int h = tid >> 3;
    const float den = dred[0][h] + dred[1][h] + dred[2][h] + dred[3][h];
    od[(size_t)r * HC + tid] = tot / den;
  }
}

// ---------------------------------------------------------------------------
// Kernel 3 (MFMA): EXACT round-2 kernel (measured 132 us). LN affine in-kernel,
// unfolded wgT/woT, bg direct. VGPR-124 schedule. Do not edit.
// ---------------------------------------------------------------------------
__global__ __launch_bounds__(128) void k3_mfma(
    const float* __restrict__ m,
    const float* __restrict__ ln_w, const float* __restrict__ ln_b,
    const short* __restrict__ wgT_hi, const short* __restrict__ wgT_lo,
    const short* __restrict__ woT_hi, const short* __restrict__ woT_lo,
    const float* __restrict__ bg, const float* __restrict__ bo,
    const float* __restrict__ od, float* __restrict__ out) {
  const int tid = threadIdx.x;
  const int wave = tid >> 6;
  const int lane = tid & 63;
  const int lrow = lane & 15;   // A/B frag row index
  const int lpart = lane >> 4;  // 0..3, k-chunk owner
  const size_t base = (size_t)blockIdx.x * 128 + (size_t)wave * 64;
  const int base_r = (int)(base % R_RES);

  __shared__ float t_lds[2][64 * 64];  // per-wave t tile, XOR-swizzled rows
  float* tw = t_lds[wave];

  // per-lane bias values for columns j = n*16 + lrow
  float bgv[4], bov[4];
  #pragma unroll
  for (int n = 0; n < 4; ++n) { bgv[n] = bg[n * 16 + lrow]; bov[n] = bo[n * 16 + lrow]; }

  // LN params for this lane's two k-chunks: c = lpart*8+e and 32+lpart*8+e
  float lw0[8], lb0[8], lw1[8], lb1[8];
  {
    const float4* w0 = reinterpret_cast<const float4*>(ln_w + lpart * 8);
    const float4* w1 = reinterpret_cast<const float4*>(ln_w + 32 + lpart * 8);
    const float4* b0 = reinterpret_cast<const float4*>(ln_b + lpart * 8);
    const float4* b1 = reinterpret_cast<const float4*>(ln_b + 32 + lpart * 8);
    float4 a = w0[0], b = w0[1], c = w1[0], d = w1[1];
    lw0[0]=a.x; lw0[1]=a.y; lw0[2]=a.z; lw0[3]=a.w; lw0[4]=b.x; lw0[5]=b.y; lw0[6]=b.z; lw0[7]=b.w;
    lw1[0]=c.x; lw1[1]=c.y; lw1[2]=c.z; lw1[3]=c.w; lw1[4]=d.x; lw1[5]=d.y; lw1[6]=d.z; lw1[7]=d.w;
    a = b0[0]; b = b0[1]; c = b1[0]; d = b1[1];
    lb0[0]=a.x; lb0[1]=a.y; lb0[2]=a.z; lb0[3]=a.w; lb0[4]=b.x; lb0[5]=b.y; lb0[6]=b.z; lb0[7]=b.w;
    lb1[0]=c.x; lb1[1]=c.y; lb1[2]=c.z; lb1[3]=c.w; lb1[4]=d.x; lb1[5]=d.y; lb1[6]=d.z; lb1[7]=d.w;
  }

  // ---- B1 frags (wgT hi/lo): [n][k], lane reads wgT[n*16+lrow][k*32 + lpart*8 ..+7]
  bf16x8 b1h[4][2], b1l[4][2];
  #pragma unroll
  for (int n = 0; n < 4; ++n) {
    #pragma unroll
    for (int k = 0; k < 2; ++k) {
      const int idx = (n * 16 + lrow) * 64 + k * 32 + lpart * 8;
      b1h[n][k] = *reinterpret_cast<const bf16x8*>(wgT_hi + idx);
      b1l[n][k] = *reinterpret_cast<const bf16x8*>(wgT_lo + idx);
    }
  }

  // ---- Pass 1: LN -> GEMM1 -> sigmoid*o -> t to LDS ----
  #pragma unroll
  for (int mt = 0; mt < 4; ++mt) {
    const size_t grow = base + mt * 16 + lrow;
    const float* mrow = m + grow * CIN;
    float x0[8], x1[8];
    {
      const float4* p0 = reinterpret_cast<const float4*>(mrow + lpart * 8);
      const float4* p1 = reinterpret_cast<const float4*>(mrow + 32 + lpart * 8);
      float4 a = p0[0], b = p0[1], c = p1[0], d = p1[1];
      x0[0]=a.x; x0[1]=a.y; x0[2]=a.z; x0[3]=a.w; x0[4]=b.x; x0[5]=b.y; x0[6]=b.z; x0[7]=b.w;
      x1[0]=c.x; x1[1]=c.y; x1[2]=c.z; x1[3]=c.w; x1[4]=d.x; x1[5]=d.y; x1[6]=d.z; x1[7]=d.w;
    }
    float s = 0.f;
    #pragma unroll
    for (int e = 0; e < 8; ++e) s += x0[e] + x1[e];
    s += __shfl_xor(s, 16, 64);
    s += __shfl_xor(s, 32, 64);
    const float mean = s * (1.0f / CIN);
    float vs = 0.f;
    #pragma unroll
    for (int e = 0; e < 8; ++e) {
      float d0 = x0[e] - mean, d1 = x1[e] - mean;
      vs += d0 * d0 + d1 * d1;
    }
    vs += __shfl_xor(vs, 16, 64);
    vs += __shfl_xor(vs, 32, 64);
    const float rstd = rsqrtf(vs * (1.0f / CIN) + 1e-5f);

    bf16x8 ah0, al0, ah1, al1;
    #pragma unroll
    for (int e = 0; e < 8; ++e) {
      float xn = (x0[e] - mean) * rstd * lw0[e] + lb0[e];
      short h = f2bf(xn);
      ah0[e] = h; al0[e] = f2bf(xn - bf2f(h));
      xn = (x1[e] - mean) * rstd * lw1[e] + lb1[e];
      h = f2bf(xn);
      ah1[e] = h; al1[e] = f2bf(xn - bf2f(h));
    }

    #pragma unroll
    for (int n = 0; n < 4; ++n) {
      f32x4 acc = {0.f, 0.f, 0.f, 0.f};
      acc = __builtin_amdgcn_mfma_f32_16x16x32_bf16(ah0, b1h[n][0], acc, 0, 0, 0);
      acc = __builtin_amdgcn_mfma_f32_16x16x32_bf16(ah1, b1h[n][1], acc, 0, 0, 0);
      acc = __builtin_amdgcn_mfma_f32_16x16x32_bf16(ah0, b1l[n][0], acc, 0, 0, 0);
      acc = __builtin_amdgcn_mfma_f32_16x16x32_bf16(ah1, b1l[n][1], acc, 0, 0, 0);
      acc = __builtin_amdgcn_mfma_f32_16x16x32_bf16(al0, b1h[n][0], acc, 0, 0, 0);
      acc = __builtin_amdgcn_mfma_f32_16x16x32_bf16(al1, b1h[n][1], acc, 0, 0, 0);
      const int j = n * 16 + lrow;
      #pragma unroll
      for (int i = 0; i < 4; ++i) {
        const int rl = mt * 16 + lpart * 4 + i;
        int r = base_r + rl; if (r >= R_RES) r -= R_RES;
        const float z = acc[i] + bgv[n];
        const float g = 1.0f / (1.0f + __expf(-z));
        const float t = g * od[(size_t)r * HC + j];
        const int off = ((rl * 256 + j * 4)) ^ ((rl & 7) << 4);
        *reinterpret_cast<float*>(reinterpret_cast<char*>(tw) + off) = t;
      }
    }
  }

  __syncthreads();  // safe ordering of LDS writes -> reads (also within wave)

  // ---- B2 frags (woT hi/lo) replace B1 ----
  bf16x8 b2h[4][2], b2l[4][2];
  #pragma unroll
  for (int n = 0; n < 4; ++n) {
    #pragma unroll
    for (int k = 0; k < 2; ++k) {
      const int idx = (n * 16 + lrow) * 64 + k * 32 + lpart * 8;
      b2h[n][k] = *reinterpret_cast<const bf16x8*>(woT_hi + idx);
      b2l[n][k] = *reinterpret_cast<const bf16x8*>(woT_lo + idx);
    }
  }

  // ---- Pass 2: t -> GEMM2 -> out ----
  #pragma unroll
  for (int mt = 0; mt < 4; ++mt) {
    const int rl2 = mt * 16 + lrow;
    const int swz = (rl2 & 7) << 4;
    bf16x8 ah0, al0, ah1, al1;
    {
      const int a0 = rl2 * 256 + lpart * 32;         // k-chunk 0: j = lpart*8..
      const int a1 = rl2 * 256 + 128 + lpart * 32;   // k-chunk 1: j = 32+lpart*8..
      char* tb = reinterpret_cast<char*>(tw);
      float4 u0 = *reinterpret_cast<float4*>(tb + (a0 ^ swz));
      float4 u1 = *reinterpret_cast<float4*>(tb + ((a0 + 16) ^ swz));
      float4 u2 = *reinterpret_cast<float4*>(tb + (a1 ^ swz));
      float4 u3 = *reinterpret_cast<float4*>(tb + ((a1 + 16) ^ swz));
      float t0[8] = {u0.x, u0.y, u0.z, u0.w, u1.x, u1.y, u1.z, u1.w};
      float t1[8] = {u2.x, u2.y, u2.z, u2.w, u3.x, u3.y, u3.z, u3.w};
      #pragma unroll
      for (int e = 0; e < 8; ++e) {
        short h = f2bf(t0[e]);
        ah0[e] = h; al0[e] = f2bf(t0[e] - bf2f(h));
        h = f2bf(t1[e]);
        ah1[e] = h; al1[e] = f2bf(t1[e] - bf2f(h));
      }
    }
    #pragma unroll
    for (int n = 0; n < 4; ++n) {
      f32x4 acc = {0.f, 0.f, 0.f, 0.f};
      acc = __builtin_amdgcn_mfma_f32_16x16x32_bf16(ah0, b2h[n][0], acc, 0, 0, 0);
      acc = __builtin_amdgcn_mfma_f32_16x16x32_bf16(ah1, b2h[n][1], acc, 0, 0, 0);
      acc = __builtin_amdgcn_mfma_f32_16x16x32_bf16(ah0, b2l[n][0], acc, 0, 0, 0);
      acc = __builtin_amdgcn_mfma_f32_16x16x32_bf16(ah1, b2l[n][1], acc, 0, 0, 0);
      acc = __builtin_amdgcn_mfma_f32_16x16x32_bf16(al0, b2h[n][0], acc, 0, 0, 0);
      acc = __builtin_amdgcn_mfma_f32_16x16x32_bf16(al1, b2h[n][1], acc, 0, 0, 0);
      const int cc = n * 16 + lrow;
      #pragma unroll
      for (int i = 0; i < 4; ++i) {
        const size_t grow = base + mt * 16 + lpart * 4 + i;
        out[grow * CIN + cc] = acc[i] + bov[n];
      }
    }
  }
}

// ---------------------------------------------------------------------------
extern "C" void kernel_launch(void* const* d_in, const int* in_sizes, int n_in,
                              void* d_out, int out_size, void* d_ws, size_t ws_size,
                              hipStream_t stream) {
  const float* m    = (const float*)d_in[0];
  const float* mask = (const float*)d_in[1];
  const float* ln_w = (const float*)d_in[2];
  const float* ln_b = (const float*)d_in[3];
  const float* wq   = (const float*)d_in[4];
  const float* wk   = (const float*)d_in[5];
  const float* wv   = (const float*)d_in[6];
  const float* wg   = (const float*)d_in[7];
  const float* bg   = (const float*)d_in[8];
  const float* wo   = (const float*)d_in[9];
  const float* bo   = (const float*)d_in[10];
  float* out = (float*)d_out;

  const size_t sizeK   = (size_t)R_RES * S_SEQ * CHD * sizeof(float);   // 25.2 MB
  const size_t sizeQP  = (size_t)4 * R_RES * CIN * sizeof(float);       // 393 KB
  const size_t sizeQM  = (size_t)4 * R_RES * sizeof(float);
  const size_t sizeO   = (size_t)R_RES * HC * sizeof(float);
  const size_t sizeW   = (size_t)HC * CIN * sizeof(short);              // 8 KB
  const size_t sizeWKV = (size_t)16 * CIN * sizeof(short);              // 2 KB

  char* ws = (char*)d_ws;
  float* Kd         = (float*)(ws);
  float* Vd         = (float*)(ws + sizeK);
  float* qpool_part = (float*)(ws + 2 * sizeK);
  float* qm_part    = (float*)(ws + 2 * sizeK + sizeQP);
  float* od         = (float*)(ws + 2 * sizeK + sizeQP + sizeQM);
  char* wbase       = ws + 2 * sizeK + sizeQP + sizeQM + sizeO;
  short* wgT_hi  = (short*)(wbase);
  short* wgT_lo  = (short*)(wbase + sizeW);
  short* woT_hi  = (short*)(wbase + 2 * sizeW);
  short* woT_lo  = (short*)(wbase + 3 * sizeW);
  short* wkvT_hi = (short*)(wbase + 4 * sizeW);
  short* wkvT_lo = (short*)(wbase + 4 * sizeW + sizeWKV);
  float* bkv     = (float*)(wbase + 4 * sizeW + 2 * sizeWKV);

  k0_prep<<<(HC * CIN + 255) / 256, 256, 0, stream>>>(
      wg, wo, wk, wv, ln_w, ln_b,
      wgT_hi, wgT_lo, woT_hi, woT_lo, wkvT_hi, wkvT_lo, bkv);

  k1_mfma<<<dim3(R_RES, 4), 256, 0, stream>>>(
      m, mask, wkvT_hi, wkvT_lo, bkv, Kd, Vd, qpool_part, qm_part);

  k2_attn<<<R_RES, 256, 0, stream>>>(
      mask, ln_w, ln_b, wq, qpool_part, qm_part, Kd, Vd, od);

  k3_mfma<<<(S_SEQ * R_RES) / 128, 128, 0, stream>>>(
      m, ln_w, ln_b, wgT_hi, wgT_lo, woT_hi, woT_lo, bg, bo, od, out);
}